// Round 6
// baseline (49.145 us; speedup 1.0000x reference)
//
#include <hip/hip_runtime.h>
#include <math.h>

constexpr int kN = 65536;
constexpr int kB = 16384;
constexpr int kTileW = 2560;   // tiered packed triangle: 16*64+16*48+16*32+16*16 words
constexpr int kElems = 2;      // batch elements per wave

static __device__ __forceinline__ float bcastf(float v, int lane) {
    union { float f; int i; } u;
    u.f = v;
    u.i = __builtin_amdgcn_readlane(u.i, lane);
    return u.f;
}

// async global->LDS; LDS dest = wave-uniform base + lane*size (active lanes only)
static __device__ __forceinline__ void gload_lds16(const float* g, float* l) {
    __builtin_amdgcn_global_load_lds(
        (const __attribute__((address_space(1))) void*)g,
        (__attribute__((address_space(3))) void*)l, 16, 0, 0);
}
static __device__ __forceinline__ void gload_lds4(const float* g, float* l) {
    __builtin_amdgcn_global_load_lds(
        (const __attribute__((address_space(1))) void*)g,
        (__attribute__((address_space(3))) void*)l, 4, 0, 0);
}

// tier layout: row j (tier t=j>>4, width w=64-16t) starts at
// off(t) + w*(j-16t), off(t) = 1024t - 128t(t-1)
static __device__ __forceinline__ int row_start(int j) {
    const int t = j >> 4;
    return 1024 * t - 128 * t * (t - 1) + (64 - 16 * t) * (j - 16 * t);
}

static __device__ __forceinline__ bool is_hot(int g) {
    return (g >= 63) && (g <= kN - 63);
}

struct EState { float uval, md, yg, mpg; };

// Issue all of one element's loads (scalars + 10 async tile loads). No waits.
static __device__ __forceinline__ EState stage_one(
    int g, int lane, float* myl,
    const float* __restrict__ Uv, const float* __restrict__ Vv,
    const float* __restrict__ mean, const float* __restrict__ mean_post,
    const float* __restrict__ y, const int* __restrict__ crow_u,
    const int* __restrict__ crow_v)
{
    const int  anc = g - 63 + lane;
    const bool vl  = (anc >= 0);
    const int  L   = (g + 1 < 64) ? (g + 1) : 64;
    const int  ub  = (g >= 63) ? (2016 + 64 * (g - 63)) : crow_u[g];

    EState s;
    s.uval = 0.0f; s.md = 0.0f;
    if (vl) {
        s.uval = Uv[ub + lane - (64 - L)];       // row g of U, last L slots
        s.md   = mean[anc] - mean_post[anc];
    }
    s.yg  = y[g];
    s.mpg = mean_post[g];

    if (is_hot(g)) {
        const float* base = Vv + 64 * (g - 63);  // contiguous 16KB row block
        // tier0: rows 0..15 full width (1024 words @ 0)
        {
            const float* src = base + 4 * lane;
            #pragma unroll
            for (int k = 0; k < 4; ++k)
                gload_lds16(src + 256 * k, myl + 256 * k);
        }
        // tier1: rows 16..31, width 48 (768 words @ 1024)
        #pragma unroll
        for (int k = 0; k < 3; ++k) {
            const int w   = 256 * k + 4 * lane;
            const int jj  = ((w >> 4) * 171) >> 9;   // exact (w/16)/3 for w<768
            const int col = w - 48 * jj;
            gload_lds16(base + 64 * (16 + jj) + col, myl + 1024 + 256 * k);
        }
        // tier2: rows 32..47, width 32 (512 words @ 1792)
        #pragma unroll
        for (int k = 0; k < 2; ++k) {
            const int w = 256 * k + 4 * lane;
            gload_lds16(base + 64 * (32 + (w >> 5)) + (w & 31), myl + 1792 + 256 * k);
        }
        // tier3: rows 48..63, width 16 (256 words @ 2304)
        {
            const int w = 4 * lane;
            gload_lds16(base + 64 * (48 + (w >> 4)) + (w & 15), myl + 2304);
        }
    } else {
        // rare: g<63 (identity rows) or band tail (crow_v irregular)
        int rowbase = 0;
        if (vl) rowbase = crow_v[anc];
        for (int j = 0; j < 64; ++j) {
            const int rbj = __builtin_amdgcn_readlane(rowbase, j);
            const int dst = row_start(j);
            if (lane < 64 - j) {                 // exactly the consumed words
                if (g - 63 + j >= 0)
                    gload_lds4(Vv + rbj + lane, myl + dst);
                else
                    myl[dst + lane] = 0.0f;      // identity row: zero off-diag
            }
        }
    }
    return s;
}

// Pre-scaled dual-RHS back-substitution; returns the element's scalar
// contribution (valid on lane 0).
static __device__ __forceinline__ float compute_one(
    int g, int lane, const float* myl, EState st, float inv2n)
{
    const int  anc = g - 63 + lane;
    const bool vl  = (anc >= 0);

    const int rs = row_start(lane);
    const float d0   = myl[rs];
    const float diag = vl ? d0 : 1.0f;           // identity rows: unit diagonal
    const float invd = 1.0f / diag;

    // v[i] = V_sub[lane][i] / diag_lane for i>=lane; i<lane reads prior rows'
    // garbage, provably unused before this lane's residual is consumed.
    const float* vrow = myl + (rs - lane);
    float v[64];
    #pragma unroll
    for (int i = 0; i < 64; ++i) v[i] = vrow[i] * invd;

    // Solve (D^-1 V) x = D^-1 rhs  (unit diagonal -> x_i = residual_i)
    float r_e = (lane == 63) ? invd : 0.0f;      // D^-1 e_{63}
    float r_u = st.uval * invd;                  // D^-1 U_sub
    float acc_e = 0.0f, acc_u = 0.0f;

    #pragma unroll
    for (int i = 63; i >= 0; --i) {
        const float s_e = bcastf(r_e, i);        // x_i for RHS e
        const float s_u = bcastf(r_u, i);        // x_i for RHS u
        r_e = fmaf(-v[i], s_e, r_e);             // on lane i: v[i]=1 -> r=0
        r_u = fmaf(-v[i], s_u, r_u);
        acc_e = fmaf(s_e, s_e, acc_e);
        acc_u = fmaf(s_u, s_u, acc_u);
    }

    // dot(U_sub, md) via wave reduction
    float dot = st.uval * st.md;
    #pragma unroll
    for (int m = 1; m < 64; m <<= 1)
        dot += __shfl_xor(dot, m, 64);

    const float ulast  = bcastf(st.uval, 63);    // U_values[crow_u[g+1]-1]
    const float vfirst = bcastf(diag, 63);       // V_values[crow_v[g]]

    const float resid = st.yg - st.mpg;
    return __logf(ulast) - __logf(vfirst)
         - 0.5f * dot * dot
         - 0.5f * acc_u
         - (resid * resid + acc_e) * inv2n;
}

__global__ __launch_bounds__(64) void gp_solve_kernel(
    const float* __restrict__ Uv,
    const float* __restrict__ Vv,
    const float* __restrict__ mean,
    const float* __restrict__ mean_post,
    const float* __restrict__ y,
    const int*   __restrict__ gidx,
    const int*   __restrict__ crow_u,
    const int*   __restrict__ crow_v,
    const float* __restrict__ noise,
    float*       __restrict__ partial)
{
    __shared__ __align__(16) float lds[kElems][kTileW];

    const int lane = (int)threadIdx.x;
    const int b0   = (int)blockIdx.x * kElems;
    const int g0   = gidx[b0];
    const int g1   = gidx[b0 + 1];

    EState s0 = stage_one(g0, lane, lds[0], Uv, Vv, mean, mean_post, y, crow_u, crow_v);
    asm volatile("" ::: "memory");   // keep A's loads older than B's
    EState s1 = stage_one(g1, lane, lds[1], Uv, Vv, mean, mean_post, y, crow_u, crow_v);

    const float inv2n = 0.5f / noise[0];

    // A's tile ready when only B's 10 async loads remain in flight.
    if (is_hot(g0) && is_hot(g1))
        asm volatile("s_waitcnt vmcnt(10) lgkmcnt(0)" ::: "memory");
    else
        asm volatile("s_waitcnt vmcnt(0) lgkmcnt(0)" ::: "memory");
    const float c0 = compute_one(g0, lane, lds[0], s0, inv2n);

    asm volatile("s_waitcnt vmcnt(0) lgkmcnt(0)" ::: "memory");
    const float c1 = compute_one(g1, lane, lds[1], s1, inv2n);

    if (lane == 0)
        partial[blockIdx.x] = c0 + c1;
}

__global__ __launch_bounds__(1024) void gp_reduce_kernel(
    const float* __restrict__ partial,
    const float* __restrict__ noise,
    float*       __restrict__ out)
{
    __shared__ float ws[16];
    const int t = (int)threadIdx.x;
    float a = 0.0f;
    #pragma unroll
    for (int k = 0; k < 2; ++k) {                // 2048 float4 = 8192 floats
        const float4 p = reinterpret_cast<const float4*>(partial)[t + 1024 * k];
        a += (p.x + p.y) + (p.z + p.w);
    }
    #pragma unroll
    for (int m = 1; m < 64; m <<= 1)
        a += __shfl_xor(a, m, 64);
    if ((t & 63) == 0) ws[t >> 6] = a;
    __syncthreads();
    if (t == 0) {
        float tot = 0.0f;
        #pragma unroll
        for (int k = 0; k < 16; ++k) tot += ws[k];
        tot += -0.5f * (float)kB * logf(2.0f * 3.14159265358979323846f * noise[0]);
        out[0] = tot;
    }
}

extern "C" void kernel_launch(void* const* d_in, const int* in_sizes, int n_in,
                              void* d_out, int out_size, void* d_ws, size_t ws_size,
                              hipStream_t stream)
{
    const float* Uv        = (const float*)d_in[0];
    const float* Vv        = (const float*)d_in[1];
    const float* mean      = (const float*)d_in[2];
    const float* mean_post = (const float*)d_in[3];
    const float* y         = (const float*)d_in[4];
    const float* noise     = (const float*)d_in[5];
    const int*   gidx      = (const int*)d_in[6];
    const int*   crow_u    = (const int*)d_in[7];
    const int*   crow_v    = (const int*)d_in[8];
    float* partial = (float*)d_ws;   // kB/kElems = 8192 floats

    gp_solve_kernel<<<dim3(kB / kElems), dim3(64), 0, stream>>>(
        Uv, Vv, mean, mean_post, y, gidx, crow_u, crow_v, noise, partial);
    gp_reduce_kernel<<<dim3(1), dim3(1024), 0, stream>>>(
        partial, noise, (float*)d_out);
}

// Round 7
// 36.943 us; speedup vs baseline: 1.3303x; 1.3303x over previous
//
#include <hip/hip_runtime.h>
#include <math.h>

constexpr int kN = 65536;
constexpr int kB = 16384;
constexpr int kTileW = 2560;   // tiered packed triangle: 16*64+16*48+16*32+16*16 words

static __device__ __forceinline__ float bcastf(float v, int lane) {
    union { float f; int i; } u;
    u.f = v;
    u.i = __builtin_amdgcn_readlane(u.i, lane);
    return u.f;
}

// async global->LDS; LDS dest = wave-uniform base + lane*size (active lanes only)
static __device__ __forceinline__ void gload_lds16(const float* g, float* l) {
    __builtin_amdgcn_global_load_lds(
        (const __attribute__((address_space(1))) void*)g,
        (__attribute__((address_space(3))) void*)l, 16, 0, 0);
}
static __device__ __forceinline__ void gload_lds4(const float* g, float* l) {
    __builtin_amdgcn_global_load_lds(
        (const __attribute__((address_space(1))) void*)g,
        (__attribute__((address_space(3))) void*)l, 4, 0, 0);
}

// tier layout: row j (tier t=j>>4, width w=64-16t) starts at
// off(t) + w*(j-16t), off(t) = 1024t - 128t(t-1)
static __device__ __forceinline__ int row_start(int j) {
    const int t = j >> 4;
    return 1024 * t - 128 * t * (t - 1) + (64 - 16 * t) * (j - 16 * t);
}

static __device__ __forceinline__ bool is_hot(int g) {
    return (g >= 63) && (g <= kN - 63);
}

__global__ __launch_bounds__(64) void gp_solve_kernel(
    const float* __restrict__ Uv,
    const float* __restrict__ Vv,
    const float* __restrict__ mean,
    const float* __restrict__ mean_post,
    const float* __restrict__ y,
    const int*   __restrict__ gidx,
    const int*   __restrict__ crow_u,
    const int*   __restrict__ crow_v,
    const float* __restrict__ noise,
    float*       __restrict__ partial)
{
    __shared__ __align__(16) float myl[kTileW];

    const int lane = (int)threadIdx.x;          // 0..63
    const int b    = (int)blockIdx.x;
    const int g    = gidx[b];

    const int  anc = g - 63 + lane;             // this lane's row index
    const bool vl  = (anc >= 0);

    // U row: crow_u[g] = 2016 + 64*(g-63) for g>=63 (U rows never shorten)
    const int L  = (g + 1 < 64) ? (g + 1) : 64;
    const int ub = (g >= 63) ? (2016 + 64 * (g - 63)) : crow_u[g];

    float uval = 0.0f, md = 0.0f;
    if (vl) {
        uval = Uv[ub + lane - (64 - L)];        // row g of U, last L slots
        md   = mean[anc] - mean_post[anc];
    }
    const float yg  = y[g];
    const float mpg = mean_post[g];

    if (is_hot(g)) {
        const float* base = Vv + 64 * (g - 63);  // contiguous 16KB row block
        // tier0: rows 0..15 full width (1024 words @ 0)
        {
            const float* src = base + 4 * lane;
            #pragma unroll
            for (int k = 0; k < 4; ++k)
                gload_lds16(src + 256 * k, myl + 256 * k);
        }
        // tier1: rows 16..31, width 48 (768 words @ 1024)
        #pragma unroll
        for (int k = 0; k < 3; ++k) {
            const int w   = 256 * k + 4 * lane;
            const int jj  = ((w >> 4) * 171) >> 9;   // exact (w/16)/3 for w<768
            const int col = w - 48 * jj;
            gload_lds16(base + 64 * (16 + jj) + col, myl + 1024 + 256 * k);
        }
        // tier2: rows 32..47, width 32 (512 words @ 1792)
        #pragma unroll
        for (int k = 0; k < 2; ++k) {
            const int w = 256 * k + 4 * lane;
            gload_lds16(base + 64 * (32 + (w >> 5)) + (w & 31), myl + 1792 + 256 * k);
        }
        // tier3: rows 48..63, width 16 (256 words @ 2304)
        {
            const int w = 4 * lane;
            gload_lds16(base + 64 * (48 + (w >> 4)) + (w & 15), myl + 2304);
        }
    } else {
        // rare (~32/16384 waves): g<63 (identity rows) or band tail (crow_v irregular)
        int rowbase = 0;
        if (vl) rowbase = crow_v[anc];
        for (int j = 0; j < 64; ++j) {
            const int rbj = __builtin_amdgcn_readlane(rowbase, j);
            const int dst = row_start(j);
            if (lane < 64 - j) {                 // exactly the consumed words
                if (g - 63 + j >= 0)
                    gload_lds4(Vv + rbj + lane, myl + dst);
                else
                    myl[dst + lane] = 0.0f;      // identity row: zero off-diag
            }
        }
    }
    // per-wave drain of global_load_lds (vmcnt) and ds_write (lgkm); the
    // "memory" clobber orders the ds_reads below behind this wait.
    asm volatile("s_waitcnt vmcnt(0) lgkmcnt(0)" ::: "memory");

    const int rs = row_start(lane);
    const float d0   = myl[rs];
    const float diag = vl ? d0 : 1.0f;           // identity rows: unit diagonal
    const float invd = 1.0f / diag;

    // v[i] = V_sub[lane][i] / diag_lane for i>=lane; i<lane reads prior rows'
    // garbage, provably unused before this lane's residual is consumed at
    // step i=lane. Paired reads -> ds_read2_b32 merge.
    const float* vrow = myl + (rs - lane);
    float v[64];
    #pragma unroll
    for (int i = 0; i < 64; i += 2) {
        const float a0 = vrow[i];
        const float a1 = vrow[i + 1];
        v[i]     = a0 * invd;
        v[i + 1] = a1 * invd;
    }

    // ---- pre-scaled dual-RHS back-substitution (unit diagonal) ----
    float r_e = (lane == 63) ? invd : 0.0f;      // D^-1 e_{63}
    float r_u = uval * invd;                     // D^-1 U_sub
    float acc_e = 0.0f, acc_u = 0.0f;

    #pragma unroll
    for (int i = 63; i >= 0; --i) {
        const float s_e = bcastf(r_e, i);        // x_i for RHS e
        const float s_u = bcastf(r_u, i);        // x_i for RHS u
        r_e = fmaf(-v[i], s_e, r_e);             // on lane i: v[i]=1 -> r=0
        r_u = fmaf(-v[i], s_u, r_u);
        acc_e = fmaf(s_e, s_e, acc_e);
        acc_u = fmaf(s_u, s_u, acc_u);
    }

    // ---- dot(U_sub, md) via wave reduction ----
    float dot = uval * md;
    #pragma unroll
    for (int m = 1; m < 64; m <<= 1)
        dot += __shfl_xor(dot, m, 64);

    const float ulast  = bcastf(uval, 63);       // U_values[crow_u[g+1]-1]
    const float vfirst = bcastf(diag, 63);       // V_values[crow_v[g]]

    if (lane == 0) {
        const float resid = yg - mpg;
        const float inv2n = 0.5f / noise[0];
        partial[b] = __logf(ulast) - __logf(vfirst)
                   - 0.5f * dot * dot
                   - 0.5f * acc_u
                   - (resid * resid + acc_e) * inv2n;
    }
}

__global__ __launch_bounds__(1024) void gp_reduce_kernel(
    const float* __restrict__ partial,
    const float* __restrict__ noise,
    float*       __restrict__ out)
{
    __shared__ float ws[16];
    const int t = (int)threadIdx.x;
    float a = 0.0f;
    #pragma unroll
    for (int k = 0; k < 4; ++k) {                // 4096 float4 = 16384 floats
        const float4 p = reinterpret_cast<const float4*>(partial)[t + 1024 * k];
        a += (p.x + p.y) + (p.z + p.w);
    }
    #pragma unroll
    for (int m = 1; m < 64; m <<= 1)
        a += __shfl_xor(a, m, 64);
    if ((t & 63) == 0) ws[t >> 6] = a;
    __syncthreads();
    if (t == 0) {
        float tot = 0.0f;
        #pragma unroll
        for (int k = 0; k < 16; ++k) tot += ws[k];
        tot += -0.5f * (float)kB * logf(2.0f * 3.14159265358979323846f * noise[0]);
        out[0] = tot;
    }
}

extern "C" void kernel_launch(void* const* d_in, const int* in_sizes, int n_in,
                              void* d_out, int out_size, void* d_ws, size_t ws_size,
                              hipStream_t stream)
{
    const float* Uv        = (const float*)d_in[0];
    const float* Vv        = (const float*)d_in[1];
    const float* mean      = (const float*)d_in[2];
    const float* mean_post = (const float*)d_in[3];
    const float* y         = (const float*)d_in[4];
    const float* noise     = (const float*)d_in[5];
    const int*   gidx      = (const int*)d_in[6];
    const int*   crow_u    = (const int*)d_in[7];
    const int*   crow_v    = (const int*)d_in[8];
    float* partial = (float*)d_ws;   // kB floats = 64 KB scratch

    gp_solve_kernel<<<dim3(kB), dim3(64), 0, stream>>>(
        Uv, Vv, mean, mean_post, y, gidx, crow_u, crow_v, noise, partial);
    gp_reduce_kernel<<<dim3(1), dim3(1024), 0, stream>>>(
        partial, noise, (float*)d_out);
}